// Round 3
// baseline (261.185 us; speedup 1.0000x reference)
//
#include <hip/hip_runtime.h>
#include <math.h>

#define Bn 8
#define Cn 64
#define Hn 128
#define Wn 128
#define HWn (Hn * Wn)
#define Kn 9

// staged-row geometry: 66 px (w0-1 .. w0+64), px stride 40 shorts (80 B = 20 dw)
#define XSW 40
#define XSROW (66 * XSW)   // 2640 shorts per row
#define XSCC (3 * XSROW)   // 7920 shorts per cc-half

typedef __attribute__((ext_vector_type(8))) short short8;
typedef __attribute__((ext_vector_type(4))) float floatx4;

__device__ __forceinline__ float bf2f(short s) {
  return __uint_as_float(((unsigned)(unsigned short)s) << 16);
}
__device__ __forceinline__ short f2bf(float f) {
  unsigned u = __float_as_uint(f);
  u += 0x7fff + ((u >> 16) & 1);  // RNE
  return (short)(u >> 16);
}

// ---------------------------------------------------------------------------
// Prep 1: weights fp32 [cout][cin][kk] -> bf16 [row][kk*64+cin].
// rows 0..31: w_om (27 real + 5 zero), 32..95: w_dc, 96..159: w_c.
// ---------------------------------------------------------------------------
__global__ __launch_bounds__(256) void k_prep_w(
    const float* __restrict__ w_om, const float* __restrict__ w_dc,
    const float* __restrict__ w_c, short* __restrict__ wt) {
  int idx = blockIdx.x * 256 + threadIdx.x;
  if (idx >= 160 * 576) return;
  int row = idx / 576, k = idx - row * 576;
  int kk = k >> 6, cin = k & 63;
  float v;
  if (row < 32)
    v = (row < 27) ? w_om[(row * 64 + cin) * 9 + kk] : 0.f;
  else if (row < 96)
    v = w_dc[((row - 32) * 64 + cin) * 9 + kk];
  else
    v = w_c[((row - 96) * 64 + cin) * 9 + kk];
  wt[idx] = f2bf(v);
}

// ---------------------------------------------------------------------------
// Prep 2: x fp32 NCHW -> bf16 half-channel-last xT2[b][half][h][w][32].
// (32-ch records make row segments contiguous for LDS staging.)
// ---------------------------------------------------------------------------
__global__ __launch_bounds__(256) void k_prep_x(const float* __restrict__ x,
                                                short* __restrict__ xT2) {
  __shared__ float tile[64][129];
  const int h = blockIdx.x, b = blockIdx.y;
  const int tid = threadIdx.x;
  const float* xb = x + (size_t)b * 64 * HWn + h * Wn;
  for (int i = tid; i < 8192; i += 256) {
    int c = i >> 7, w = i & 127;
    tile[c][w] = xb[c * HWn + w];
  }
  __syncthreads();
  for (int i = tid; i < 2048; i += 256) {
    int w = i >> 4, c4 = (i & 15) * 4;
    int half = c4 >> 5, cl = c4 & 31;
    short4 o;
    o.x = f2bf(tile[c4 + 0][w]);
    o.y = f2bf(tile[c4 + 1][w]);
    o.z = f2bf(tile[c4 + 2][w]);
    o.w = f2bf(tile[c4 + 3][w]);
    *(short4*)(xT2 + ((size_t)(b * 2 + half) * HWn + h * Wn + w) * 32 + cl) = o;
  }
}

// ---------------------------------------------------------------------------
// Fused kernel: conv_om (M=32) -> offsets/mask in LDS -> modulated deformable
// conv (M=64) + bias + leaky-ReLU -> actT2 bf16 half-channel-last.
// Grid (2,128,8), 256 threads. LDS = 37.9 KB (union) -> 4 blocks/CU.
// ---------------------------------------------------------------------------
__global__ __launch_bounds__(256, 4) void k_omdef(
    const short* __restrict__ xT2, const short* __restrict__ wt,
    const float* __restrict__ b_om, const float* __restrict__ b_dc,
    short* __restrict__ actT2) {
  // union: phase1 {xs: 15840 B, som: 7020 B} vs phase2 {val: 37888 B}
  __shared__ __attribute__((aligned(16))) char raw[64 * 296 * 2];
  short* xs = (short*)raw;                  // [3][66][XSW]
  float* som = (float*)(raw + XSCC * 2);    // [27][65]
  short(*val)[296] = (short(*)[296])raw;    // [px][kk*32+c]

  const int b = blockIdx.z, h = blockIdx.y, w0 = blockIdx.x * 64;
  const int tid = threadIdx.x;
  const int wave = tid >> 6, lane = tid & 63, quad = lane >> 4, lr = lane & 15;
  const short* xb2 = xT2 + (size_t)b * 2 * HWn * 32;

  // ================= phase 1: conv_om =================
  floatx4 zf = {0.f, 0.f, 0.f, 0.f};
  floatx4 aco0 = zf, aco1 = zf;
  const int mo0 = (wave & 1) * 16;
  const int n0 = (wave >> 1) * 32;

  for (int cc = 0; cc < 2; ++cc) {
    if (cc) __syncthreads();  // xs readers done before restage
    for (int j = tid; j < 792; j += 256) {
      int c8 = (j & 3) * 8;
      int r = j >> 2;            // 0..197
      int ky = r / 66, p = r - ky * 66;
      int gy = h + ky - 1, gx = w0 - 1 + p;
      short8 v = {0, 0, 0, 0, 0, 0, 0, 0};
      if (gy >= 0 && gy < Hn && gx >= 0 && gx < Wn)
        v = *(const short8*)(xb2 + ((size_t)cc * HWn + gy * Wn + gx) * 32 + c8);
      *(short8*)(xs + ky * XSROW + p * XSW + c8) = v;
    }
    __syncthreads();
    const short* wbo = wt + cc * 32 + quad * 8;
#pragma unroll
    for (int kk = 0; kk < 9; ++kk) {
      int ky = kk / 3, kx = kk - ky * 3;
      short8 a = *(const short8*)(wbo + (mo0 + lr) * 576 + kk * 64);
      const short* bp = xs + ky * XSROW + kx * XSW + quad * 8;
      short8 b0 = *(const short8*)(bp + (n0 + lr) * XSW);
      short8 b1 = *(const short8*)(bp + (n0 + 16 + lr) * XSW);
      aco0 = __builtin_amdgcn_mfma_f32_16x16x32_bf16(a, b0, aco0, 0, 0, 0);
      aco1 = __builtin_amdgcn_mfma_f32_16x16x32_bf16(a, b1, aco1, 0, 0, 0);
    }
  }
  // om epilogue -> som[cout][px] (mask rows get 2*sigmoid)
#pragma unroll
  for (int nt = 0; nt < 2; ++nt) {
    floatx4 a = nt ? aco1 : aco0;
    int px = n0 + nt * 16 + lr;
#pragma unroll
    for (int r = 0; r < 4; ++r) {
      int co = mo0 + quad * 4 + r;
      if (co < 27) {
        float v = a[r] + b_om[co];
        if (co >= 18) v = 2.f / (1.f + expf(-v));
        som[co * 65 + px] = v;
      }
    }
  }
  __syncthreads();

  // ================= phase A: bilinear params -> registers =================
  // pair t covers (k,px) = tid + t*256; packed: 2x u16 addr, 2x bf16 weight
  unsigned pa01[3], pa23[3], pu01[3], pu23[3];
#pragma unroll
  for (int t = 0; t < 3; ++t) {
    int pr = tid + t * 256;
    if (pr < 576) {
      int k = pr >> 6, p = pr & 63;
      float offy = som[(2 * k) * 65 + p];
      float offx = som[(2 * k + 1) * 65 + p];
      float m = som[(18 + k) * 65 + p];
      float py = (float)(h - 1 + (k / 3)) + offy;
      float px_ = (float)(w0 + p - 1 + (k % 3)) + offx;
      float fy = floorf(py), fx = floorf(px_);
      float ly = py - fy, lx = px_ - fx;
      int iy0 = (int)fy, ix0 = (int)fx;
      int iy1 = iy0 + 1, ix1 = ix0 + 1;
      bool vy0 = (iy0 >= 0) && (iy0 < Hn);
      bool vy1 = (iy1 >= 0) && (iy1 < Hn);
      bool vx0 = (ix0 >= 0) && (ix0 < Wn);
      bool vx1 = (ix1 >= 0) && (ix1 < Wn);
      unsigned cy0 = (unsigned)min(max(iy0, 0), Hn - 1);
      unsigned cy1 = (unsigned)min(max(iy1, 0), Hn - 1);
      unsigned cx0 = (unsigned)min(max(ix0, 0), Wn - 1);
      unsigned cx1 = (unsigned)min(max(ix1, 0), Wn - 1);
      pa01[t] = (cy0 * Wn + cx0) | ((cy0 * Wn + cx1) << 16);
      pa23[t] = (cy1 * Wn + cx0) | ((cy1 * Wn + cx1) << 16);
      float u0 = (vy0 && vx0) ? (1.f - ly) * (1.f - lx) * m : 0.f;
      float u1 = (vy0 && vx1) ? (1.f - ly) * lx * m : 0.f;
      float u2 = (vy1 && vx0) ? ly * (1.f - lx) * m : 0.f;
      float u3 = (vy1 && vx1) ? ly * lx * m : 0.f;
      pu01[t] = (unsigned)(unsigned short)f2bf(u0) |
                ((unsigned)(unsigned short)f2bf(u1) << 16);
      pu23[t] = (unsigned)(unsigned short)f2bf(u2) |
                ((unsigned)(unsigned short)f2bf(u3) << 16);
    }
  }
  __syncthreads();  // phase A reads of som done before val overwrites

  // ================= phase 2: deformable conv =================
  floatx4 acc[2][2] = {{zf, zf}, {zf, zf}};
  const int m0 = (wave & 1) * 32;

  for (int cc = 0; cc < 2; ++cc) {
    if (cc) __syncthreads();
#pragma unroll
    for (int t = 0; t < 3; ++t) {
      int pr = tid + t * 256;
      if (pr < 576) {
        int k = pr >> 6, p = pr & 63;
        int a0 = pa01[t] & 0xFFFF, a1 = pa01[t] >> 16;
        int a2 = pa23[t] & 0xFFFF, a3 = pa23[t] >> 16;
        float u0 = bf2f((short)(pu01[t] & 0xFFFF));
        float u1 = bf2f((short)(pu01[t] >> 16));
        float u2 = bf2f((short)(pu23[t] & 0xFFFF));
        float u3 = bf2f((short)(pu23[t] >> 16));
        const short* s0 = xb2 + ((size_t)cc * HWn + a0) * 32;
        const short* s1 = xb2 + ((size_t)cc * HWn + a1) * 32;
        const short* s2 = xb2 + ((size_t)cc * HWn + a2) * 32;
        const short* s3 = xb2 + ((size_t)cc * HWn + a3) * 32;
#pragma unroll
        for (int c8 = 0; c8 < 32; c8 += 8) {
          short8 q0 = *(const short8*)(s0 + c8);
          short8 q1 = *(const short8*)(s1 + c8);
          short8 q2 = *(const short8*)(s2 + c8);
          short8 q3 = *(const short8*)(s3 + c8);
          short8 o;
#pragma unroll
          for (int e = 0; e < 8; ++e) {
            float f = u0 * bf2f(q0[e]) + u1 * bf2f(q1[e]) +
                      u2 * bf2f(q2[e]) + u3 * bf2f(q3[e]);
            o[e] = f2bf(f);
          }
          *(short8*)&val[p][k * 32 + c8] = o;
        }
      }
    }
    __syncthreads();
    const short* wbd = wt + 32 * 576 + cc * 32 + quad * 8;
#pragma unroll
    for (int kk = 0; kk < 9; ++kk) {
      short8 a0 = *(const short8*)(wbd + (m0 + lr) * 576 + kk * 64);
      short8 a1 = *(const short8*)(wbd + (m0 + 16 + lr) * 576 + kk * 64);
      short8 b0 = *(const short8*)&val[n0 + lr][kk * 32 + quad * 8];
      short8 b1 = *(const short8*)&val[n0 + 16 + lr][kk * 32 + quad * 8];
      acc[0][0] = __builtin_amdgcn_mfma_f32_16x16x32_bf16(a0, b0, acc[0][0], 0, 0, 0);
      acc[0][1] = __builtin_amdgcn_mfma_f32_16x16x32_bf16(a0, b1, acc[0][1], 0, 0, 0);
      acc[1][0] = __builtin_amdgcn_mfma_f32_16x16x32_bf16(a1, b0, acc[1][0], 0, 0, 0);
      acc[1][1] = __builtin_amdgcn_mfma_f32_16x16x32_bf16(a1, b1, acc[1][1], 0, 0, 0);
    }
  }

  // epilogue: bias + leaky ReLU -> actT2[b][half][h][w][32]
#pragma unroll
  for (int mt = 0; mt < 2; ++mt) {
#pragma unroll
    for (int nt = 0; nt < 2; ++nt) {
      int px = n0 + nt * 16 + lr;
      int c0 = m0 + mt * 16 + quad * 4;
      int half = c0 >> 5, cl = c0 & 31;
      short4 o;
      float v;
      v = acc[mt][nt][0] + b_dc[c0 + 0]; o.x = f2bf(v > 0.f ? v : 0.2f * v);
      v = acc[mt][nt][1] + b_dc[c0 + 1]; o.y = f2bf(v > 0.f ? v : 0.2f * v);
      v = acc[mt][nt][2] + b_dc[c0 + 2]; o.z = f2bf(v > 0.f ? v : 0.2f * v);
      v = acc[mt][nt][3] + b_dc[c0 + 3]; o.w = f2bf(v > 0.f ? v : 0.2f * v);
      *(short4*)(actT2 +
                 ((size_t)(b * 2 + half) * HWn + h * Wn + w0 + px) * 32 + cl) = o;
    }
  }
}

// ---------------------------------------------------------------------------
// Kernel 3: conv_out via MFMA with direct B-reads from staged act rows.
// Single sync; epilogue bias + residual x -> out fp32 NCHW.
// Grid (2,128,8), 256 threads. LDS 31.7 KB -> 5 blocks/CU.
// ---------------------------------------------------------------------------
__global__ __launch_bounds__(256, 5) void k_conv_out(
    const short* __restrict__ actT2, const short* __restrict__ wt,
    const float* __restrict__ b_c, const float* __restrict__ x,
    float* __restrict__ out) {
  __shared__ __attribute__((aligned(16))) short as_[2 * XSCC];

  const int b = blockIdx.z, h = blockIdx.y, w0 = blockIdx.x * 64;
  const int tid = threadIdx.x;
  const int wave = tid >> 6, lane = tid & 63, quad = lane >> 4, lr = lane & 15;
  const short* ab2 = actT2 + (size_t)b * 2 * HWn * 32;

  for (int j = tid; j < 1584; j += 256) {
    int cc = j / 792, r = j - cc * 792;
    int c8 = (r & 3) * 8;
    int r2 = r >> 2;
    int ky = r2 / 66, p = r2 - ky * 66;
    int gy = h + ky - 1, gx = w0 - 1 + p;
    short8 v = {0, 0, 0, 0, 0, 0, 0, 0};
    if (gy >= 0 && gy < Hn && gx >= 0 && gx < Wn)
      v = *(const short8*)(ab2 + ((size_t)cc * HWn + gy * Wn + gx) * 32 + c8);
    *(short8*)(as_ + cc * XSCC + ky * XSROW + p * XSW + c8) = v;
  }
  __syncthreads();

  floatx4 zf = {0.f, 0.f, 0.f, 0.f};
  floatx4 acc[2][2] = {{zf, zf}, {zf, zf}};
  const int m0 = (wave & 1) * 32;
  const int n0 = (wave >> 1) * 32;

  for (int cc = 0; cc < 2; ++cc) {
    const short* wbc = wt + 96 * 576 + cc * 32 + quad * 8;
#pragma unroll
    for (int kk = 0; kk < 9; ++kk) {
      int ky = kk / 3, kx = kk - ky * 3;
      short8 a0 = *(const short8*)(wbc + (m0 + lr) * 576 + kk * 64);
      short8 a1 = *(const short8*)(wbc + (m0 + 16 + lr) * 576 + kk * 64);
      const short* bp = as_ + cc * XSCC + ky * XSROW + kx * XSW + quad * 8;
      short8 b0 = *(const short8*)(bp + (n0 + lr) * XSW);
      short8 b1 = *(const short8*)(bp + (n0 + 16 + lr) * XSW);
      acc[0][0] = __builtin_amdgcn_mfma_f32_16x16x32_bf16(a0, b0, acc[0][0], 0, 0, 0);
      acc[0][1] = __builtin_amdgcn_mfma_f32_16x16x32_bf16(a0, b1, acc[0][1], 0, 0, 0);
      acc[1][0] = __builtin_amdgcn_mfma_f32_16x16x32_bf16(a1, b0, acc[1][0], 0, 0, 0);
      acc[1][1] = __builtin_amdgcn_mfma_f32_16x16x32_bf16(a1, b1, acc[1][1], 0, 0, 0);
    }
  }

#pragma unroll
  for (int mt = 0; mt < 2; ++mt) {
#pragma unroll
    for (int nt = 0; nt < 2; ++nt) {
      int px = n0 + nt * 16 + lr;
#pragma unroll
      for (int r = 0; r < 4; ++r) {
        int cout = m0 + mt * 16 + quad * 4 + r;
        size_t gidx = ((size_t)(b * 64 + cout) * Hn + h) * Wn + w0 + px;
        out[gidx] = acc[mt][nt][r] + b_c[cout] + x[gidx];
      }
    }
  }
}

// ---------------------------------------------------------------------------
extern "C" void kernel_launch(void* const* d_in, const int* in_sizes, int n_in,
                              void* d_out, int out_size, void* d_ws,
                              size_t ws_size, hipStream_t stream) {
  const float* x = (const float*)d_in[0];
  const float* w_om = (const float*)d_in[1];
  const float* b_om = (const float*)d_in[2];
  const float* w_dc = (const float*)d_in[3];
  const float* b_dc = (const float*)d_in[4];
  const float* w_c = (const float*)d_in[5];
  const float* b_c = (const float*)d_in[6];
  float* out = (float*)d_out;

  // ws: xT2 bf16 (16.8 MB) | actT2 bf16 (16.8 MB) | weights bf16 (184 KB)
  short* xT2 = (short*)d_ws;
  short* actT2 = xT2 + (size_t)Bn * 2 * HWn * 32;
  short* wt = actT2 + (size_t)Bn * 2 * HWn * 32;

  k_prep_w<<<dim3((160 * 576 + 255) / 256), 256, 0, stream>>>(w_om, w_dc, w_c, wt);
  k_prep_x<<<dim3(Hn, Bn), 256, 0, stream>>>(x, xT2);
  k_omdef<<<dim3(2, Hn, Bn), 256, 0, stream>>>(xT2, wt, b_om, b_dc, actT2);
  k_conv_out<<<dim3(2, Hn, Bn), 256, 0, stream>>>(actT2, wt, b_c, x, out);
}

// Round 4
// 237.502 us; speedup vs baseline: 1.0997x; 1.0997x over previous
//
#include <hip/hip_runtime.h>
#include <math.h>

#define Bn 8
#define Cn 64
#define Hn 128
#define Wn 128
#define HWn (Hn * Wn)
#define Kn 9

// staged-row geometry: 66 px, px stride 36 shorts (18 dw -> 16 distinct banks)
#define XSW 36
#define XSROW (66 * XSW)   // 2376 shorts per row
#define XSCC (3 * XSROW)   // 7128 shorts per cc-half
#define VSTRIDE 292        // val row stride in shorts (146 dw -> 18-dw pattern)

// weight fragment regions (shorts)
#define WOM_OFF 0
#define WDC_OFF 18432
#define WC_OFF 55296

typedef __attribute__((ext_vector_type(8))) short short8;
typedef __attribute__((ext_vector_type(4))) float floatx4;

__device__ __forceinline__ float bf2f(short s) {
  return __uint_as_float(((unsigned)(unsigned short)s) << 16);
}
__device__ __forceinline__ short f2bf(float f) {
  unsigned u = __float_as_uint(f);
  u += 0x7fff + ((u >> 16) & 1);  // RNE
  return (short)(u >> 16);
}

// ---------------------------------------------------------------------------
// Prep 1: weights -> bf16 MFMA-A-fragment order, so a wave's A-load is one
// contiguous 1KB coalesced load: frag[(cc*9+kk)*MT + mt][lane][8elem],
// lane=quad*16+lr holds row=mt*16+lr, cin=cc*32+quad*8+elem, tap kk.
// ---------------------------------------------------------------------------
__global__ __launch_bounds__(256) void k_prep_w(
    const float* __restrict__ w_om, const float* __restrict__ w_dc,
    const float* __restrict__ w_c, short* __restrict__ wt) {
  int idx = blockIdx.x * 256 + threadIdx.x;
  if (idx >= 92160) return;
  float v;
  if (idx < WDC_OFF) {  // om region, MT=2 m-tiles (M=32)
    int e = idx;
    int elem = e & 7, lane = (e >> 3) & 63, mt = (e >> 9) & 1, t = e >> 10;
    int kk = t % 9, cc = t / 9;
    int row = mt * 16 + (lane & 15);
    int cin = cc * 32 + (lane >> 4) * 8 + elem;
    v = (row < 27) ? w_om[(row * 64 + cin) * 9 + kk] : 0.f;
  } else {  // dc / c regions, MT=4 m-tiles (M=64)
    int e = (idx < WC_OFF) ? idx - WDC_OFF : idx - WC_OFF;
    const float* src = (idx < WC_OFF) ? w_dc : w_c;
    int elem = e & 7, lane = (e >> 3) & 63, mt = (e >> 9) & 3, t = e >> 11;
    int kk = t % 9, cc = t / 9;
    int row = mt * 16 + (lane & 15);
    int cin = cc * 32 + (lane >> 4) * 8 + elem;
    v = src[(row * 64 + cin) * 9 + kk];
  }
  wt[idx] = f2bf(v);
}

// ---------------------------------------------------------------------------
// Prep 2: x fp32 NCHW -> bf16 channels-last xT[b][h][w][64] (128B records).
// 1D grid 1024, b = bid&7 for XCD locality.
// ---------------------------------------------------------------------------
__global__ __launch_bounds__(256) void k_prep_x(const float* __restrict__ x,
                                                short* __restrict__ xT) {
  __shared__ float tile[64][129];
  const int bid = blockIdx.x;
  const int b = bid & 7, h = bid >> 3;
  const int tid = threadIdx.x;
  const float* xb = x + (size_t)b * 64 * HWn + h * Wn;
  for (int i = tid; i < 8192; i += 256) {
    int c = i >> 7, w = i & 127;
    tile[c][w] = xb[c * HWn + w];
  }
  __syncthreads();
  short* dst = xT + ((size_t)(b * Hn + h) * Wn) * 64;
  for (int i = tid; i < 2048; i += 256) {
    int w = i >> 4, c4 = (i & 15) * 4;
    short4 o;
    o.x = f2bf(tile[c4 + 0][w]);
    o.y = f2bf(tile[c4 + 1][w]);
    o.z = f2bf(tile[c4 + 2][w]);
    o.w = f2bf(tile[c4 + 3][w]);
    *(short4*)(dst + (size_t)w * 64 + c4) = o;
  }
}

// ---------------------------------------------------------------------------
// Fused: conv_om -> som(LDS) -> bilinear params(LDS, packed) -> modulated
// deformable conv + bias + leakyReLU -> actT bf16 channels-last.
// 1D grid 2048 (b = bid&7). LDS 46.6KB -> 3 blocks/CU.
// ---------------------------------------------------------------------------
__global__ __launch_bounds__(256, 3) void k_omdef(
    const short* __restrict__ xT, const short* __restrict__ wt,
    const float* __restrict__ b_om, const float* __restrict__ b_dc,
    short* __restrict__ actT) {
  // region 0..37375: phase1 {xs 14256B, som 7020B} / phase2 {val 64x292 sh}
  // region 37376..46591: packed bilinear params (survive phase 2)
  __shared__ __attribute__((aligned(16))) char raw[64 * VSTRIDE * 2 + 9216];
  short* xs = (short*)raw;                      // [3][66][XSW]
  float* som = (float*)(raw + XSCC * 2);        // [27][65]
  short(*val)[VSTRIDE] = (short(*)[VSTRIDE])raw;
  unsigned* sbw = (unsigned*)(raw + 64 * VSTRIDE * 2);
  unsigned* sb01 = sbw, *sb23 = sbw + 576, *sw01 = sbw + 1152,
          *sw23 = sbw + 1728;

  const int bid = blockIdx.x;
  const int b = bid & 7;
  const int r = bid >> 3;
  const int h = r >> 1, w0 = (r & 1) * 64;
  const int tid = threadIdx.x;
  const int wave = tid >> 6, lane = tid & 63, quad = lane >> 4, lr = lane & 15;
  const short* xb = xT + (size_t)b * HWn * 64;

  // ================= phase 1: conv_om =================
  floatx4 zf = {0.f, 0.f, 0.f, 0.f};
  floatx4 aco0 = zf, aco1 = zf;
  const int mto = wave & 1;         // om m-tile (M=32)
  const int n0 = (wave >> 1) * 32;  // px tile

  for (int cc = 0; cc < 2; ++cc) {
    if (cc) __syncthreads();
    for (int j = tid; j < 792; j += 256) {
      int c8 = (j & 3) * 8;
      int rr = j >> 2;  // 0..197
      int ky = rr / 66, p = rr - ky * 66;
      int gy = h + ky - 1, gx = w0 - 1 + p;
      short8 v = {0, 0, 0, 0, 0, 0, 0, 0};
      if (gy >= 0 && gy < Hn && gx >= 0 && gx < Wn)
        v = *(const short8*)(xb + (size_t)(gy * Wn + gx) * 64 + cc * 32 + c8);
      *(short8*)(xs + ky * XSROW + p * XSW + c8) = v;
    }
    __syncthreads();
#pragma unroll
    for (int kk = 0; kk < 9; ++kk) {
      int ky = kk / 3, kx = kk - ky * 3;
      short8 a = *(const short8*)(wt + WOM_OFF +
                                  (((cc * 9 + kk) * 2 + mto) * 64 + lane) * 8);
      const short* bp = xs + ky * XSROW + kx * XSW + quad * 8;
      short8 b0 = *(const short8*)(bp + (n0 + lr) * XSW);
      short8 b1 = *(const short8*)(bp + (n0 + 16 + lr) * XSW);
      aco0 = __builtin_amdgcn_mfma_f32_16x16x32_bf16(a, b0, aco0, 0, 0, 0);
      aco1 = __builtin_amdgcn_mfma_f32_16x16x32_bf16(a, b1, aco1, 0, 0, 0);
    }
  }
  // om epilogue -> som[cout][px]
#pragma unroll
  for (int nt = 0; nt < 2; ++nt) {
    floatx4 a = nt ? aco1 : aco0;
    int px = n0 + nt * 16 + lr;
#pragma unroll
    for (int rr = 0; rr < 4; ++rr) {
      int co = mto * 16 + quad * 4 + rr;
      if (co < 27) {
        float v = a[rr] + b_om[co];
        if (co >= 18) v = 2.f / (1.f + expf(-v));
        som[co * 65 + px] = v;
      }
    }
  }
  __syncthreads();

  // ================= phase A: bilinear params -> packed LDS =================
  for (int pr = tid; pr < 576; pr += 256) {
    int k = pr >> 6, p = pr & 63;
    float offy = som[(2 * k) * 65 + p];
    float offx = som[(2 * k + 1) * 65 + p];
    float m = som[(18 + k) * 65 + p];
    float py = (float)(h - 1 + (k / 3)) + offy;
    float px_ = (float)(w0 + p - 1 + (k % 3)) + offx;
    float fy = floorf(py), fx = floorf(px_);
    float ly = py - fy, lx = px_ - fx;
    int iy0 = (int)fy, ix0 = (int)fx;
    int iy1 = iy0 + 1, ix1 = ix0 + 1;
    bool vy0 = (iy0 >= 0) && (iy0 < Hn);
    bool vy1 = (iy1 >= 0) && (iy1 < Hn);
    bool vx0 = (ix0 >= 0) && (ix0 < Wn);
    bool vx1 = (ix1 >= 0) && (ix1 < Wn);
    unsigned cy0 = (unsigned)min(max(iy0, 0), Hn - 1);
    unsigned cy1 = (unsigned)min(max(iy1, 0), Hn - 1);
    unsigned cx0 = (unsigned)min(max(ix0, 0), Wn - 1);
    unsigned cx1 = (unsigned)min(max(ix1, 0), Wn - 1);
    sb01[pr] = (cy0 * Wn + cx0) | ((cy0 * Wn + cx1) << 16);
    sb23[pr] = (cy1 * Wn + cx0) | ((cy1 * Wn + cx1) << 16);
    float u0 = (vy0 && vx0) ? (1.f - ly) * (1.f - lx) * m : 0.f;
    float u1 = (vy0 && vx1) ? (1.f - ly) * lx * m : 0.f;
    float u2 = (vy1 && vx0) ? ly * (1.f - lx) * m : 0.f;
    float u3 = (vy1 && vx1) ? ly * lx * m : 0.f;
    sw01[pr] = (unsigned)(unsigned short)f2bf(u0) |
               ((unsigned)(unsigned short)f2bf(u1) << 16);
    sw23[pr] = (unsigned)(unsigned short)f2bf(u2) |
               ((unsigned)(unsigned short)f2bf(u3) << 16);
  }
  __syncthreads();  // params ready; som/xs reads done before val overwrite

  // ================= phase 2: deformable conv =================
  floatx4 acc[2][2] = {{zf, zf}, {zf, zf}};
  const int mt0 = (wave & 1) * 2;  // m-tiles {mt0, mt0+1} (M=64)

  for (int cc = 0; cc < 2; ++cc) {
    if (cc) __syncthreads();
    // fill: 4 lanes per (k,px), each lane one 16B chunk of a 64B corner-line
    for (int j = tid; j < 2304; j += 256) {
      int chunk = j & 3, pr = j >> 2;
      int p = pr & 63, k = pr >> 6;
      unsigned a01 = sb01[pr], a23 = sb23[pr];
      unsigned uw01 = sw01[pr], uw23 = sw23[pr];
      float u0 = bf2f((short)(uw01 & 0xFFFF));
      float u1 = bf2f((short)(uw01 >> 16));
      float u2 = bf2f((short)(uw23 & 0xFFFF));
      float u3 = bf2f((short)(uw23 >> 16));
      int co = cc * 32 + chunk * 8;
      short8 q0 = *(const short8*)(xb + (size_t)(a01 & 0xFFFF) * 64 + co);
      short8 q1 = *(const short8*)(xb + (size_t)(a01 >> 16) * 64 + co);
      short8 q2 = *(const short8*)(xb + (size_t)(a23 & 0xFFFF) * 64 + co);
      short8 q3 = *(const short8*)(xb + (size_t)(a23 >> 16) * 64 + co);
      short8 o;
#pragma unroll
      for (int e = 0; e < 8; ++e) {
        float f = u0 * bf2f(q0[e]) + u1 * bf2f(q1[e]) + u2 * bf2f(q2[e]) +
                  u3 * bf2f(q3[e]);
        o[e] = f2bf(f);
      }
      *(short8*)&val[p][k * 32 + chunk * 8] = o;
    }
    __syncthreads();
#pragma unroll
    for (int kk = 0; kk < 9; ++kk) {
      short8 a0 = *(const short8*)(wt + WDC_OFF +
                                   (((cc * 9 + kk) * 4 + mt0) * 64 + lane) * 8);
      short8 a1 = *(const short8*)(wt + WDC_OFF +
                                   (((cc * 9 + kk) * 4 + mt0 + 1) * 64 + lane) * 8);
      short8 b0 = *(const short8*)&val[n0 + lr][kk * 32 + quad * 8];
      short8 b1 = *(const short8*)&val[n0 + 16 + lr][kk * 32 + quad * 8];
      acc[0][0] = __builtin_amdgcn_mfma_f32_16x16x32_bf16(a0, b0, acc[0][0], 0, 0, 0);
      acc[0][1] = __builtin_amdgcn_mfma_f32_16x16x32_bf16(a0, b1, acc[0][1], 0, 0, 0);
      acc[1][0] = __builtin_amdgcn_mfma_f32_16x16x32_bf16(a1, b0, acc[1][0], 0, 0, 0);
      acc[1][1] = __builtin_amdgcn_mfma_f32_16x16x32_bf16(a1, b1, acc[1][1], 0, 0, 0);
    }
  }

  // epilogue: bias + leaky ReLU -> actT[b][h][w][64]
  short* ab = actT + ((size_t)(b * Hn + h) * Wn + w0) * 64;
#pragma unroll
  for (int mt = 0; mt < 2; ++mt) {
#pragma unroll
    for (int nt = 0; nt < 2; ++nt) {
      int px = n0 + nt * 16 + lr;
      int c0 = (mt0 + mt) * 16 + quad * 4;
      short4 o;
      float v;
      v = acc[mt][nt][0] + b_dc[c0 + 0]; o.x = f2bf(v > 0.f ? v : 0.2f * v);
      v = acc[mt][nt][1] + b_dc[c0 + 1]; o.y = f2bf(v > 0.f ? v : 0.2f * v);
      v = acc[mt][nt][2] + b_dc[c0 + 2]; o.z = f2bf(v > 0.f ? v : 0.2f * v);
      v = acc[mt][nt][3] + b_dc[c0 + 3]; o.w = f2bf(v > 0.f ? v : 0.2f * v);
      *(short4*)(ab + (size_t)px * 64 + c0) = o;
    }
  }
}

// ---------------------------------------------------------------------------
// conv_out: stage 3 act rows (both halves), direct shifted B-reads, single
// sync. Epilogue bias + residual -> out fp32 NCHW. 1D grid 2048 (b=bid&7).
// LDS 28.5KB -> 5 blocks/CU.
// ---------------------------------------------------------------------------
__global__ __launch_bounds__(256, 5) void k_conv_out(
    const short* __restrict__ actT, const short* __restrict__ wt,
    const float* __restrict__ b_c, const float* __restrict__ x,
    float* __restrict__ out) {
  __shared__ __attribute__((aligned(16))) short as_[2 * XSCC];

  const int bid = blockIdx.x;
  const int b = bid & 7;
  const int r = bid >> 3;
  const int h = r >> 1, w0 = (r & 1) * 64;
  const int tid = threadIdx.x;
  const int wave = tid >> 6, lane = tid & 63, quad = lane >> 4, lr = lane & 15;
  const short* ab = actT + (size_t)b * HWn * 64;

  for (int j = tid; j < 1584; j += 256) {
    int cc = j / 792, rr = j - cc * 792;
    int c8 = (rr & 3) * 8;
    int r2 = rr >> 2;
    int ky = r2 / 66, p = r2 - ky * 66;
    int gy = h + ky - 1, gx = w0 - 1 + p;
    short8 v = {0, 0, 0, 0, 0, 0, 0, 0};
    if (gy >= 0 && gy < Hn && gx >= 0 && gx < Wn)
      v = *(const short8*)(ab + (size_t)(gy * Wn + gx) * 64 + cc * 32 + c8);
    *(short8*)(as_ + cc * XSCC + ky * XSROW + p * XSW + c8) = v;
  }
  __syncthreads();

  floatx4 zf = {0.f, 0.f, 0.f, 0.f};
  floatx4 acc[2][2] = {{zf, zf}, {zf, zf}};
  const int mt0 = (wave & 1) * 2;
  const int n0 = (wave >> 1) * 32;

  for (int cc = 0; cc < 2; ++cc) {
#pragma unroll
    for (int kk = 0; kk < 9; ++kk) {
      int ky = kk / 3, kx = kk - ky * 3;
      short8 a0 = *(const short8*)(wt + WC_OFF +
                                   (((cc * 9 + kk) * 4 + mt0) * 64 + lane) * 8);
      short8 a1 = *(const short8*)(wt + WC_OFF +
                                   (((cc * 9 + kk) * 4 + mt0 + 1) * 64 + lane) * 8);
      const short* bp = as_ + cc * XSCC + ky * XSROW + kx * XSW + quad * 8;
      short8 b0 = *(const short8*)(bp + (n0 + lr) * XSW);
      short8 b1 = *(const short8*)(bp + (n0 + 16 + lr) * XSW);
      acc[0][0] = __builtin_amdgcn_mfma_f32_16x16x32_bf16(a0, b0, acc[0][0], 0, 0, 0);
      acc[0][1] = __builtin_amdgcn_mfma_f32_16x16x32_bf16(a0, b1, acc[0][1], 0, 0, 0);
      acc[1][0] = __builtin_amdgcn_mfma_f32_16x16x32_bf16(a1, b0, acc[1][0], 0, 0, 0);
      acc[1][1] = __builtin_amdgcn_mfma_f32_16x16x32_bf16(a1, b1, acc[1][1], 0, 0, 0);
    }
  }

#pragma unroll
  for (int mt = 0; mt < 2; ++mt) {
#pragma unroll
    for (int nt = 0; nt < 2; ++nt) {
      int px = n0 + nt * 16 + lr;
#pragma unroll
      for (int rr = 0; rr < 4; ++rr) {
        int cout = (mt0 + mt) * 16 + quad * 4 + rr;
        size_t gidx = ((size_t)(b * 64 + cout) * Hn + h) * Wn + w0 + px;
        out[gidx] = acc[mt][nt][rr] + b_c[cout] + x[gidx];
      }
    }
  }
}

// ---------------------------------------------------------------------------
extern "C" void kernel_launch(void* const* d_in, const int* in_sizes, int n_in,
                              void* d_out, int out_size, void* d_ws,
                              size_t ws_size, hipStream_t stream) {
  const float* x = (const float*)d_in[0];
  const float* w_om = (const float*)d_in[1];
  const float* b_om = (const float*)d_in[2];
  const float* w_dc = (const float*)d_in[3];
  const float* b_dc = (const float*)d_in[4];
  const float* w_c = (const float*)d_in[5];
  const float* b_c = (const float*)d_in[6];
  float* out = (float*)d_out;

  // ws: xT bf16 (16.8 MB) | actT bf16 (16.8 MB) | weight frags (184 KB)
  short* xT = (short*)d_ws;
  short* actT = xT + (size_t)Bn * HWn * 64;
  short* wt = actT + (size_t)Bn * HWn * 64;

  k_prep_w<<<dim3(360), 256, 0, stream>>>(w_om, w_dc, w_c, wt);
  k_prep_x<<<dim3(1024), 256, 0, stream>>>(x, xT);
  k_omdef<<<dim3(2048), 256, 0, stream>>>(xT, wt, b_om, b_dc, actT);
  k_conv_out<<<dim3(2048), 256, 0, stream>>>(actT, wt, b_c, x, out);
}